// Round 5
// baseline (370.390 us; speedup 1.0000x reference)
//
#include <hip/hip_runtime.h>

// Problem constants
#define T_STEPS 8
#define NROW    42            // C*Dp = 3*14
#define BN      2688          // B*NROW = 64*42
#define KFLAT   5376          // NROW*H1

// Row layout is t-minor: m = (b*42 + c*14 + dp)*8 + t. Each thread's 8-row
// micro-tile = one neuron-group's full time axis -> LIF runs in the GEMM
// epilogue registers (bit-identical chain to a separate LIF kernel).

// LDS column swizzle: +4 floats every 32 -> power-of-2 stride groups stay
// conflict-free. Row stride 68 floats.
#define SWA(r)  ((r) + ((r) >> 5) * 4)

// ---------------------------------------------------------------------------
// K1: avg-pool3d (2,2,2)/(2,2,2) VALID; writes pr in t-minor row layout.
// Pure HBM-bound, 21504 blocks.
// ---------------------------------------------------------------------------
__global__ __launch_bounds__(256) void pool_kernel(const float* __restrict__ x,
                                                   float* __restrict__ pr) {
    int idx = blockIdx.x * 256 + threadIdx.x;      // < 5,505,024
    int f   = idx & 255;
    int wp  = f & 15, hp = f >> 4;
    int rest = idx >> 8;                           // (t,b,c,dp), 21504 total
    int dp = rest % 14;
    int r2 = rest / 14;
    int c  = r2 % 3;
    int r3 = r2 / 3;
    int b  = r3 & 63;
    int t  = r3 >> 6;
    const float* base = x + ((long)b * 712704 + (long)c * 237568
                          + (long)(t * 29 + 2 * dp) * 1024
                          + (2 * hp) * 32 + 2 * wp);
    float2 v0 = *(const float2*)(base);
    float2 v1 = *(const float2*)(base + 32);
    float2 v2 = *(const float2*)(base + 1024);
    float2 v3 = *(const float2*)(base + 1056);
    float s = v0.x + v0.y + v1.x + v1.y + v2.x + v2.y + v3.x + v3.y;
    int m = (b * NROW + c * 14 + dp) * 8 + t;      // t-minor
    pr[(long)m * 256 + f] = s * 0.125f;
}

// ---------------------------------------------------------------------------
// K2/K3: fused  spk = LIF(A @ B^T + bias).
// 64x64 tile, 256 threads, 8x2 micro-tile (8 rows = one group's 8 timesteps).
// Grid: (N/64) x 336  ->  1344 blocks (L1) / 672 (L2): ~21 waves/CU resident,
// enough TLP to hide global-load latency across the staging barriers.
// Per k-iter per wave: 2x ds_read_b128 (A) + 1x ds_read_b64 (B) ~30 cyc vs
// 16 fma = 32 cyc -> VALU-bound at instruction level.
// ---------------------------------------------------------------------------
__global__ __launch_bounds__(256, 4) void gemm_lif(
        const float* __restrict__ A,      // [21504][K]
        const float* __restrict__ B,      // [N][K]
        const float* __restrict__ bias,
        const float* __restrict__ beta,
        const float* __restrict__ thr,
        float* __restrict__ spk,          // [21504][N], t-minor rows
        int N, int K) {
    __shared__ float At[16 * 68];
    __shared__ float Bt[16 * 68];
    int tid = threadIdx.x;
    int m0 = blockIdx.y * 64;
    int n0 = blockIdx.x * 64;

    // staging: 64 rows x 4 k-quads each for A and B
    int sr = tid >> 2, sq = tid & 3;
    int scol = SWA(sr);
    const float* Ap = A + (long)(m0 + sr) * K + sq * 4;
    const float* Bp = B + (long)(n0 + sr) * K + sq * 4;

    // compute map: 8 row-groups x 32 col-pairs
    int tm = tid & 7, tn = tid >> 3;      // tn 0..31
    int ca = SWA(tm * 8);
    int cb = SWA(tn * 2);

    float acc[8][2] = {};

    for (int k0 = 0; k0 < K; k0 += 16) {
        float4 a = *(const float4*)(Ap + k0);
        float4 b = *(const float4*)(Bp + k0);
        __syncthreads();
        int ks = sq * 4;
        At[(ks + 0) * 68 + scol] = a.x; At[(ks + 1) * 68 + scol] = a.y;
        At[(ks + 2) * 68 + scol] = a.z; At[(ks + 3) * 68 + scol] = a.w;
        Bt[(ks + 0) * 68 + scol] = b.x; Bt[(ks + 1) * 68 + scol] = b.y;
        Bt[(ks + 2) * 68 + scol] = b.z; Bt[(ks + 3) * 68 + scol] = b.w;
        __syncthreads();
#pragma unroll
        for (int k = 0; k < 16; ++k) {
            float4 av0 = *(const float4*)&At[k * 68 + ca];
            float4 av1 = *(const float4*)&At[k * 68 + ca + 4];
            float2 bv  = *(const float2*)&Bt[k * 68 + cb];
            float am[8] = {av0.x, av0.y, av0.z, av0.w, av1.x, av1.y, av1.z, av1.w};
#pragma unroll
            for (int i = 0; i < 8; ++i) {
                acc[i][0] = fmaf(am[i], bv.x, acc[i][0]);
                acc[i][1] = fmaf(am[i], bv.y, acc[i][1]);
            }
        }
    }

    // ---- LIF epilogue: micro-tile row i == timestep t of group tm ----
#pragma unroll
    for (int j = 0; j < 2; ++j) {
        int h = n0 + tn * 2 + j;
        float be = fminf(fmaxf(beta[h], 0.f), 1.f);
        float th = thr[h];
        float bi = bias[h];
        float mem = 0.f;
#pragma unroll
        for (int t = 0; t < T_STEPS; ++t) {
            float cur = acc[t][j] + bi;
            float reset = (mem > th) ? th : 0.f;
            mem = be * mem + cur - reset;
            acc[t][j] = ((mem - th) > 0.f) ? 1.f : 0.f;
        }
    }
    int rbase = m0 + tm * 8;
    int col = n0 + tn * 2;
#pragma unroll
    for (int t = 0; t < T_STEPS; ++t) {
        float2 o = {acc[t][0], acc[t][1]};
        *(float2*)&spk[(long)(rbase + t) * N + col] = o;
    }
}

// ---------------------------------------------------------------------------
// K4: cur_out[row=(t*64+b)][cls], reading spk_hid in t-minor layout.
// (unchanged — preserves the passing reduction order)
// ---------------------------------------------------------------------------
__global__ __launch_bounds__(256) void out_gemm(const float* __restrict__ spkh,
                                                const float* __restrict__ W_out,
                                                const float* __restrict__ b_out,
                                                float* __restrict__ cur_out) {
    __shared__ float part[256][8];
    int row = blockIdx.x;                    // t*64 + b
    int t = row >> 6, b = row & 63;
    int tid = threadIdx.x;
    float acc[6] = {0.f, 0.f, 0.f, 0.f, 0.f, 0.f};
    for (int j = tid; j < KFLAT; j += 256) {
        int n = j >> 7, h = j & 127;
        float s = spkh[((long)(b * NROW + n) * 8 + t) * 128 + h];
#pragma unroll
        for (int c = 0; c < 6; ++c)
            acc[c] = fmaf(s, W_out[c * KFLAT + j], acc[c]);
    }
#pragma unroll
    for (int c = 0; c < 6; ++c) part[tid][c] = acc[c];
    __syncthreads();
    for (int off = 128; off > 0; off >>= 1) {
        if (tid < off) {
#pragma unroll
            for (int c = 0; c < 6; ++c) part[tid][c] += part[tid + off][c];
        }
        __syncthreads();
    }
    if (tid < 6) cur_out[row * 6 + tid] = part[0][tid] + b_out[tid];
}

// ---------------------------------------------------------------------------
// K5: output-layer LIF (threshold 1.0), writes spikes (8,64,6) to d_out
// ---------------------------------------------------------------------------
__global__ void lif_out_kernel(const float* __restrict__ cur_out,
                               const float* __restrict__ beta_out,
                               float* __restrict__ out) {
    int j = threadIdx.x;                     // < 384, j = b*6 + cls
    if (j >= 384) return;
    int cls = j % 6;
    float be = fminf(fmaxf(beta_out[cls], 0.f), 1.f);
    float mem = 0.f;
#pragma unroll
    for (int t = 0; t < T_STEPS; ++t) {
        float cur = cur_out[t * 384 + j];
        float reset = (mem > 1.f) ? 1.f : 0.f;
        mem = be * mem + cur - reset;
        out[t * 384 + j] = ((mem - 1.f) > 0.f) ? 1.f : 0.f;
    }
}

extern "C" void kernel_launch(void* const* d_in, const int* in_sizes, int n_in,
                              void* d_out, int out_size, void* d_ws, size_t ws_size,
                              hipStream_t stream) {
    (void)in_sizes; (void)n_in; (void)out_size; (void)ws_size;
    const float* x        = (const float*)d_in[0];
    const float* W_in     = (const float*)d_in[1];
    const float* b_in     = (const float*)d_in[2];
    const float* W_hid    = (const float*)d_in[3];
    const float* b_hid    = (const float*)d_in[4];
    const float* W_out    = (const float*)d_in[5];
    const float* b_out    = (const float*)d_in[6];
    const float* beta_in  = (const float*)d_in[7];
    const float* thr_in   = (const float*)d_in[8];
    const float* beta_hid = (const float*)d_in[9];
    const float* thr_hid  = (const float*)d_in[10];
    const float* beta_out = (const float*)d_in[11];
    float* out = (float*)d_out;

    float* buf0 = (float*)d_ws;            // pr, later spk_hid (5,505,024 floats)
    float* buf1 = buf0 + 5505024;          // spk_in (5,505,024 floats)
    float* curo = buf1 + 5505024;          // 3,072 floats

    // 1. pool: x -> pr (buf0), t-minor rows
    pool_kernel<<<21504, 256, 0, stream>>>(x, buf0);
    // 2. spk_in = LIF(pr @ W_in^T + b_in): buf0 -> buf1, 1344 blocks
    gemm_lif<<<dim3(4, 336), 256, 0, stream>>>(buf0, W_in, b_in, beta_in, thr_in,
                                               buf1, 256, 256);
    // 3. spk_hid = LIF(spk_in @ W_hid^T + b_hid): buf1 -> buf0, 672 blocks
    gemm_lif<<<dim3(2, 336), 256, 0, stream>>>(buf1, W_hid, b_hid, beta_hid, thr_hid,
                                               buf0, 128, 256);
    // 4. cur_out_all: (t,b) rows x 5376 -> 6
    out_gemm<<<512, 256, 0, stream>>>(buf0, W_out, b_out, curo);
    // 5. output LIF -> d_out
    lif_out_kernel<<<1, 384, 0, stream>>>(curo, beta_out, out);
}

// Round 6
// 362.299 us; speedup vs baseline: 1.0223x; 1.0223x over previous
//
#include <hip/hip_runtime.h>

// Problem constants
#define T_STEPS 8
#define NROW    42            // C*Dp = 3*14
#define BN      2688          // B*NROW = 64*42
#define KFLAT   5376          // NROW*H1

// Row layout is t-minor: m = (b*42 + c*14 + dp)*8 + t. Each thread's 8-row
// micro-tile = one neuron-group's full time axis -> LIF runs in the GEMM
// epilogue registers (bit-identical chain to a separate LIF kernel).

// LDS column swizzle: +4 floats every 32 -> power-of-2 stride groups stay
// conflict-free. Row stride 68 floats.
#define SWA(r)  ((r) + ((r) >> 5) * 4)

// ---------------------------------------------------------------------------
// K1: avg-pool3d (2,2,2)/(2,2,2) VALID; writes pr in t-minor row layout.
// ---------------------------------------------------------------------------
__global__ __launch_bounds__(256) void pool_kernel(const float* __restrict__ x,
                                                   float* __restrict__ pr) {
    int idx = blockIdx.x * 256 + threadIdx.x;      // < 5,505,024
    int f   = idx & 255;
    int wp  = f & 15, hp = f >> 4;
    int rest = idx >> 8;                           // (t,b,c,dp), 21504 total
    int dp = rest % 14;
    int r2 = rest / 14;
    int c  = r2 % 3;
    int r3 = r2 / 3;
    int b  = r3 & 63;
    int t  = r3 >> 6;
    const float* base = x + ((long)b * 712704 + (long)c * 237568
                          + (long)(t * 29 + 2 * dp) * 1024
                          + (2 * hp) * 32 + 2 * wp);
    float2 v0 = *(const float2*)(base);
    float2 v1 = *(const float2*)(base + 32);
    float2 v2 = *(const float2*)(base + 1024);
    float2 v3 = *(const float2*)(base + 1056);
    float s = v0.x + v0.y + v1.x + v1.y + v2.x + v2.y + v3.x + v3.y;
    int m = (b * NROW + c * 14 + dp) * 8 + t;      // t-minor
    pr[(long)m * 256 + f] = s * 0.125f;
}

// ---------------------------------------------------------------------------
// K2/K3: fused  spk = LIF(A @ B^T + bias), SOFTWARE-PIPELINED K-loop.
// 64x64 tile, 256 threads, 8x2 micro-tile (8 rows = one group's 8 timesteps).
// Pipeline: regs hold chunk k; barrier; ds_write; barrier; ISSUE loads for
// chunk k+1; compute chunk k from LDS. The ~300-cyc global latency hides
// under the ~1000-cyc FMA loop instead of draining inside the barrier.
// Compute map tn=tid&31 -> wave stores are 2x256B contiguous runs.
// ---------------------------------------------------------------------------
__global__ __launch_bounds__(256, 6) void gemm_lif(
        const float* __restrict__ A,      // [21504][K]
        const float* __restrict__ B,      // [N][K]
        const float* __restrict__ bias,
        const float* __restrict__ beta,
        const float* __restrict__ thr,
        float* __restrict__ spk,          // [21504][N], t-minor rows
        int N, int K) {
    __shared__ float At[16 * 68];
    __shared__ float Bt[16 * 68];
    int tid = threadIdx.x;
    int m0 = blockIdx.y * 64;
    int n0 = blockIdx.x * 64;

    // staging: 64 rows x 4 k-quads each for A and B
    int sr = tid >> 2, sq = tid & 3;
    int scol = SWA(sr);
    int ks = sq * 4;
    const float* Ap = A + (long)(m0 + sr) * K + sq * 4;
    const float* Bp = B + (long)(n0 + sr) * K + sq * 4;

    // compute map: tn = tid&31 (col-pairs), tm = tid>>5 (row-groups)
    int tn = tid & 31, tm = tid >> 5;
    int ca = SWA(tm * 8);
    int cb = SWA(tn * 2);

    float acc[8][2] = {};

    // prologue: prefetch chunk 0
    float4 a = *(const float4*)(Ap);
    float4 b = *(const float4*)(Bp);

    for (int k0 = 0; k0 < K; k0 += 16) {
        __syncthreads();
        At[(ks + 0) * 68 + scol] = a.x; At[(ks + 1) * 68 + scol] = a.y;
        At[(ks + 2) * 68 + scol] = a.z; At[(ks + 3) * 68 + scol] = a.w;
        Bt[(ks + 0) * 68 + scol] = b.x; Bt[(ks + 1) * 68 + scol] = b.y;
        Bt[(ks + 2) * 68 + scol] = b.z; Bt[(ks + 3) * 68 + scol] = b.w;
        __syncthreads();
        // issue next chunk's loads BEFORE the compute loop (latency hides
        // under the 16-deep FMA loop; consumed after next barrier)
        if (k0 + 16 < K) {
            a = *(const float4*)(Ap + k0 + 16);
            b = *(const float4*)(Bp + k0 + 16);
        }
#pragma unroll
        for (int k = 0; k < 16; ++k) {
            float4 av0 = *(const float4*)&At[k * 68 + ca];
            float4 av1 = *(const float4*)&At[k * 68 + ca + 4];
            float2 bv  = *(const float2*)&Bt[k * 68 + cb];
            float am[8] = {av0.x, av0.y, av0.z, av0.w, av1.x, av1.y, av1.z, av1.w};
#pragma unroll
            for (int i = 0; i < 8; ++i) {
                acc[i][0] = fmaf(am[i], bv.x, acc[i][0]);
                acc[i][1] = fmaf(am[i], bv.y, acc[i][1]);
            }
        }
    }

    // ---- LIF epilogue: micro-tile row i == timestep t of group tm ----
#pragma unroll
    for (int j = 0; j < 2; ++j) {
        int h = n0 + tn * 2 + j;
        float be = fminf(fmaxf(beta[h], 0.f), 1.f);
        float th = thr[h];
        float bi = bias[h];
        float mem = 0.f;
#pragma unroll
        for (int t = 0; t < T_STEPS; ++t) {
            float cur = acc[t][j] + bi;
            float reset = (mem > th) ? th : 0.f;
            mem = be * mem + cur - reset;
            acc[t][j] = ((mem - th) > 0.f) ? 1.f : 0.f;
        }
    }
    int rbase = m0 + tm * 8;
    int col = n0 + tn * 2;
#pragma unroll
    for (int t = 0; t < T_STEPS; ++t) {
        float2 o = {acc[t][0], acc[t][1]};
        *(float2*)&spk[(long)(rbase + t) * N + col] = o;
    }
}

// ---------------------------------------------------------------------------
// K4: cur_out[row=(t*64+b)][cls], reading spk_hid in t-minor layout.
// ---------------------------------------------------------------------------
__global__ __launch_bounds__(256) void out_gemm(const float* __restrict__ spkh,
                                                const float* __restrict__ W_out,
                                                const float* __restrict__ b_out,
                                                float* __restrict__ cur_out) {
    __shared__ float part[256][8];
    int row = blockIdx.x;                    // t*64 + b
    int t = row >> 6, b = row & 63;
    int tid = threadIdx.x;
    float acc[6] = {0.f, 0.f, 0.f, 0.f, 0.f, 0.f};
    for (int j = tid; j < KFLAT; j += 256) {
        int n = j >> 7, h = j & 127;
        float s = spkh[((long)(b * NROW + n) * 8 + t) * 128 + h];
#pragma unroll
        for (int c = 0; c < 6; ++c)
            acc[c] = fmaf(s, W_out[c * KFLAT + j], acc[c]);
    }
#pragma unroll
    for (int c = 0; c < 6; ++c) part[tid][c] = acc[c];
    __syncthreads();
    for (int off = 128; off > 0; off >>= 1) {
        if (tid < off) {
#pragma unroll
            for (int c = 0; c < 6; ++c) part[tid][c] += part[tid + off][c];
        }
        __syncthreads();
    }
    if (tid < 6) cur_out[row * 6 + tid] = part[0][tid] + b_out[tid];
}

// ---------------------------------------------------------------------------
// K5: output-layer LIF (threshold 1.0), writes spikes (8,64,6) to d_out
// ---------------------------------------------------------------------------
__global__ void lif_out_kernel(const float* __restrict__ cur_out,
                               const float* __restrict__ beta_out,
                               float* __restrict__ out) {
    int j = threadIdx.x;                     // < 384, j = b*6 + cls
    if (j >= 384) return;
    int cls = j % 6;
    float be = fminf(fmaxf(beta_out[cls], 0.f), 1.f);
    float mem = 0.f;
#pragma unroll
    for (int t = 0; t < T_STEPS; ++t) {
        float cur = cur_out[t * 384 + j];
        float reset = (mem > 1.f) ? 1.f : 0.f;
        mem = be * mem + cur - reset;
        out[t * 384 + j] = ((mem - 1.f) > 0.f) ? 1.f : 0.f;
    }
}

extern "C" void kernel_launch(void* const* d_in, const int* in_sizes, int n_in,
                              void* d_out, int out_size, void* d_ws, size_t ws_size,
                              hipStream_t stream) {
    (void)in_sizes; (void)n_in; (void)out_size; (void)ws_size;
    const float* x        = (const float*)d_in[0];
    const float* W_in     = (const float*)d_in[1];
    const float* b_in     = (const float*)d_in[2];
    const float* W_hid    = (const float*)d_in[3];
    const float* b_hid    = (const float*)d_in[4];
    const float* W_out    = (const float*)d_in[5];
    const float* b_out    = (const float*)d_in[6];
    const float* beta_in  = (const float*)d_in[7];
    const float* thr_in   = (const float*)d_in[8];
    const float* beta_hid = (const float*)d_in[9];
    const float* thr_hid  = (const float*)d_in[10];
    const float* beta_out = (const float*)d_in[11];
    float* out = (float*)d_out;

    float* buf0 = (float*)d_ws;            // pr, later spk_hid (5,505,024 floats)
    float* buf1 = buf0 + 5505024;          // spk_in (5,505,024 floats)
    float* curo = buf1 + 5505024;          // 3,072 floats

    // 1. pool: x -> pr (buf0), t-minor rows
    pool_kernel<<<21504, 256, 0, stream>>>(x, buf0);
    // 2. spk_in = LIF(pr @ W_in^T + b_in): buf0 -> buf1, 1344 blocks
    gemm_lif<<<dim3(4, 336), 256, 0, stream>>>(buf0, W_in, b_in, beta_in, thr_in,
                                               buf1, 256, 256);
    // 3. spk_hid = LIF(spk_in @ W_hid^T + b_hid): buf1 -> buf0, 672 blocks
    gemm_lif<<<dim3(2, 336), 256, 0, stream>>>(buf1, W_hid, b_hid, beta_hid, thr_hid,
                                               buf0, 128, 256);
    // 4. cur_out_all: (t,b) rows x 5376 -> 6
    out_gemm<<<512, 256, 0, stream>>>(buf0, W_out, b_out, curo);
    // 5. output LIF -> d_out
    lif_out_kernel<<<1, 384, 0, stream>>>(curo, beta_out, out);
}